// Round 12
// baseline (34.461 us; speedup 1.0000x reference)
//
#include <hip/hip_runtime.h>
#include <hip/hip_bf16.h>
#include <stdint.h>

// Chamfer distance, B=2, N=M=8192, fp32 3-D points — MFMA, two transposed passes.
//
// d2[t][q] = |t|^2 + |q|^2 - 2 t.q inside v_mfma_f32_32x32x16_bf16 via
// split-bf16 (hi+lo), K=16 (encoding verified R3-R11: absmax 0.0):
//   A_k (target): [-2h(xyz), -2h(xyz), -2l(xyz), -2l(xyz), h2, l2, 1, 1]
//   B_k (query) : [  h(xyz),   l(xyz),   h(xyz),   l(xyz), 1, 1, h2, l2]
// mfma(A=targets, B=queries): lane holds 16 targets x 1 query (col=lane&31)
// -> per-lane running min is ONE scalar; fold = 8 v_min3 per MFMA (floor).
//
// R12 vs R11 (33.6us): GEOMETRY. R11's 1024 blocks at ~3 resident/CU = 1.33
// scheduling rounds (33% tail idle). Now 128 queries/wave (4 B-frags) ->
// 512 queries x 1024 targets per block -> grid 16x8x4 = 512 blocks = exactly
// 2/CU co-resident, single round, zero tail. Bonus: 1 ds_read feeds 4 MFMAs.

typedef __attribute__((ext_vector_type(8))) short short8v;
typedef __attribute__((ext_vector_type(16))) float f32x16;

#define NP 8192
#define NCHUNK 8
#define CHUNKCOLS 1024           // targets per chunk (staged in LDS)
#define QPB 512                  // queries per block (4 waves x 128)
#define SCALE 0.390625f          // 80^2 / (2 * 8192)

// ws byte offsets
#define OFF_ROW 0u         // float[4 db][8 chunk][8192]  per-chunk query mins (1 MB)
#define OFF_A   2097152u   // uint4[4 db][2 half][8192]   target planes (1 MB)
#define OFF_B   4194304u   // uint4[4 db][2 half][8192]   query planes (1 MB)

__device__ inline uint32_t f2u(float f){ union{float f;uint32_t u;}c; c.f=f; return c.u; }
__device__ inline float u2f(uint32_t u){ union{float f;uint32_t u;}c; c.u=u; return c.f; }
__device__ inline uint16_t bfr(float f){ uint32_t u=f2u(f); return (uint16_t)((u + 0x7FFFu + ((u>>16)&1u))>>16); }
__device__ inline float bff(uint16_t s){ return u2f(((uint32_t)s)<<16); }
__device__ inline float min3f(float a,float b,float c){ return fminf(fminf(a,b),c); }

// fold 16 MFMA result regs + rm -> rm : exactly 8 v_min3
__device__ inline float fold16(float rm, const f32x16& m) {
  const float a = min3f(m[0],m[1],m[2]);
  const float b = min3f(m[3],m[4],m[5]);
  const float c = min3f(m[6],m[7],m[8]);
  const float d = min3f(m[9],m[10],m[11]);
  const float e = min3f(m[12],m[13],m[14]);
  const float f = min3f(a,b,c);
  const float g = min3f(d,e,m[15]);
  return min3f(rm, f, g);
}

__device__ inline uint4 packA(float x, float y, float z, int half) {
  const uint16_t hx=bfr(x), hy=bfr(y), hz=bfr(z);
  const uint16_t lx=bfr(x-bff(hx)), ly=bfr(y-bff(hy)), lz=bfr(z-bff(hz));
  const float s2 = fmaf(x,x,fmaf(y,y,z*z));
  const uint16_t h2=bfr(s2), l2=bfr(s2-bff(h2));
  const uint16_t nhx=bfr(-2.f*bff(hx)), nhy=bfr(-2.f*bff(hy)), nhz=bfr(-2.f*bff(hz));
  const uint16_t nlx=bfr(-2.f*bff(lx)), nly=bfr(-2.f*bff(ly)), nlz=bfr(-2.f*bff(lz));
  union{ ushort u[16]; uint4 v[2]; } A;
  A.u[0]=nhx; A.u[1]=nhy; A.u[2]=nhz; A.u[3]=nhx; A.u[4]=nhy; A.u[5]=nhz;
  A.u[6]=nlx; A.u[7]=nly; A.u[8]=nlz; A.u[9]=nlx; A.u[10]=nly; A.u[11]=nlz;
  A.u[12]=h2; A.u[13]=l2; A.u[14]=0x3F80; A.u[15]=0x3F80;
  return A.v[half];
}

__device__ inline uint4 packB(float x, float y, float z, int half) {
  const uint16_t hx=bfr(x), hy=bfr(y), hz=bfr(z);
  const uint16_t lx=bfr(x-bff(hx)), ly=bfr(y-bff(hy)), lz=bfr(z-bff(hz));
  const float s2 = fmaf(x,x,fmaf(y,y,z*z));
  const uint16_t h2=bfr(s2), l2=bfr(s2-bff(h2));
  union{ ushort u[16]; uint4 v[2]; } B;
  B.u[0]=hx; B.u[1]=hy; B.u[2]=hz; B.u[3]=lx; B.u[4]=ly; B.u[5]=lz;
  B.u[6]=hx; B.u[7]=hy; B.u[8]=hz; B.u[9]=lx; B.u[10]=ly; B.u[11]=lz;
  B.u[12]=0x3F80; B.u[13]=0x3F80; B.u[14]=h2; B.u[15]=l2;
  return B.v[half];
}

// ---------------- prep: pack target (A) and query (B) k-half planes ----------
__global__ __launch_bounds__(256) void prep_kernel(
    const float* __restrict__ pred, const float* __restrict__ gt,
    float* __restrict__ out, uint8_t* __restrict__ ws) {
  const int tid = blockIdx.x*256 + (int)threadIdx.x;   // 0..65535
  if (tid == 0) out[0] = 0.0f;
  const int col  = tid & 8191;
  const int half = (tid >> 13) & 1;
  const int db   = tid >> 14;          // dir*2 + b
  const int dir = db >> 1, b = db & 1;

  // dir0: queries=pred, targets=gt.  dir1: queries=gt, targets=pred.
  const float* tsrc = (dir == 0 ? gt : pred) + ((size_t)b*NP + col)*3;
  const float* qsrc = (dir == 0 ? pred : gt) + ((size_t)b*NP + col)*3;

  ((uint4*)(ws + OFF_A))[tid] = packA(tsrc[0], tsrc[1], tsrc[2], half);
  ((uint4*)(ws + OFF_B))[tid] = packB(qsrc[0], qsrc[1], qsrc[2], half);
}

// ---------------- main MFMA kernel ----------------
__global__ __launch_bounds__(256, 2) void chamfer_mfma_kernel(uint8_t* __restrict__ ws) {
  const int wave = threadIdx.x >> 6, lane = threadIdx.x & 63;
  const int half = lane >> 5, l31 = lane & 31;
  const int qblk  = blockIdx.x;             // 0..15 (512 queries per block)
  const int chunk = blockIdx.y;             // 0..7  (1024 targets per chunk)
  const int db    = blockIdx.z;             // dir*2 + b

  __shared__ uint4 ldsA[2][CHUNKCOLS];      // 32 KB target planes

  // ---- stage this chunk's target planes (both k-halves)
  const uint4* AP = (const uint4*)(ws + OFF_A) + (size_t)db*2*NP
                    + (size_t)chunk*CHUNKCOLS;
#pragma unroll
  for (int k = 0; k < 8; ++k) {
    const int gidx = k*256 + (int)threadIdx.x;   // 0..2047
    const int h = gidx >> 10, c = gidx & 1023;
    ((uint4*)ldsA)[gidx] = AP[(size_t)h*NP + c];
  }

  // ---- the wave's 128 queries: four fixed B-fragments (L2-hot global reads)
  const uint4* BP = (const uint4*)(ws + OFF_B) + (size_t)db*2*NP + (size_t)half*NP;
  const int qbase = qblk*QPB + wave*128;
  const short8v bfrag0 = *(const short8v*)&BP[qbase      + l31];
  const short8v bfrag1 = *(const short8v*)&BP[qbase + 32 + l31];
  const short8v bfrag2 = *(const short8v*)&BP[qbase + 64 + l31];
  const short8v bfrag3 = *(const short8v*)&BP[qbase + 96 + l31];

  float rm0 = 3.4e38f, rm1 = 3.4e38f, rm2 = 3.4e38f, rm3 = 3.4e38f;
  const f32x16 zero = {};

  __syncthreads();

  // ---- 32 tiles x {1 ds_read_b128 (targets), 4 MFMA, 32 v_min3}
  const uint4* la = &ldsA[half][l31];
#pragma unroll 2
  for (int t = 0; t < 32; ++t) {
    const short8v af = *(const short8v*)(la + t*32);
    const f32x16 m0 = __builtin_amdgcn_mfma_f32_32x32x16_bf16(af, bfrag0, zero, 0,0,0);
    const f32x16 m1 = __builtin_amdgcn_mfma_f32_32x32x16_bf16(af, bfrag1, zero, 0,0,0);
    const f32x16 m2 = __builtin_amdgcn_mfma_f32_32x32x16_bf16(af, bfrag2, zero, 0,0,0);
    const f32x16 m3 = __builtin_amdgcn_mfma_f32_32x32x16_bf16(af, bfrag3, zero, 0,0,0);
    rm0 = fold16(rm0, m0);
    rm1 = fold16(rm1, m1);
    rm2 = fold16(rm2, m2);
    rm3 = fold16(rm3, m3);
  }

  // ---- cross-half combine (halves hold complementary target rows of the
  // same query col) + store
  rm0 = fminf(rm0, __shfl_xor(rm0, 32));
  rm1 = fminf(rm1, __shfl_xor(rm1, 32));
  rm2 = fminf(rm2, __shfl_xor(rm2, 32));
  rm3 = fminf(rm3, __shfl_xor(rm3, 32));

  float* wr = (float*)(ws + OFF_ROW) + ((size_t)db*NCHUNK + chunk)*NP + qbase;
  if (half == 0) {
    wr[l31]      = rm0;
    wr[32 + l31] = rm1;
    wr[64 + l31] = rm2;
    wr[96 + l31] = rm3;
  }
}

// ---------------- final reduce ----------------
__global__ __launch_bounds__(256) void reduce_kernel(
    const uint8_t* __restrict__ ws, float* __restrict__ out) {
  const float* WROW = (const float*)(ws + OFF_ROW);
  const int tid = blockIdx.x*256 + (int)threadIdx.x;  // 0..32767
  const int db = tid >> 13, q = tid & 8191;

  const float* pr = WROW + (size_t)db*NCHUNK*NP + q;
  float mn = 3.4e38f;
#pragma unroll
  for (int k = 0; k < NCHUNK; ++k) mn = fminf(mn, pr[(size_t)k*NP]);
  float sum = fmaxf(mn, 0.0f);  // clamp == ref's maximum(d2,0)

#pragma unroll
  for (int off=32; off>0; off>>=1) sum += __shfl_down(sum, off);
  __shared__ float red[4];
  if ((threadIdx.x & 63) == 0) red[threadIdx.x >> 6] = sum;
  __syncthreads();
  if (threadIdx.x == 0) atomicAdd(out, (red[0]+red[1]+red[2]+red[3]) * SCALE);
}

extern "C" void kernel_launch(void* const* d_in, const int* in_sizes, int n_in,
                              void* d_out, int out_size, void* d_ws, size_t ws_size,
                              hipStream_t stream) {
  const float* pred = (const float*)d_in[0];
  const float* gt = (const float*)d_in[1];
  float* out = (float*)d_out;
  uint8_t* ws = (uint8_t*)d_ws;

  prep_kernel<<<256, 256, 0, stream>>>(pred, gt, out, ws);
  chamfer_mfma_kernel<<<dim3(NP/QPB, NCHUNK, 4), 256, 0, stream>>>(ws);
  reduce_kernel<<<128, 256, 0, stream>>>(ws, out);
}